// Round 3
// baseline (14672.656 us; speedup 1.0000x reference)
//
#include <hip/hip_runtime.h>

typedef unsigned short u16;
typedef unsigned int   u32;
typedef __attribute__((ext_vector_type(8))) short s8v;   // 8 x bf16 (4 VGPRs)
typedef __attribute__((ext_vector_type(4))) float f4v;   // MFMA accumulator

#define DEVI __device__ __forceinline__

// ---- problem constants ----
#define B_  16
#define N_  5
#define T_  10
#define H_  512
#define E_  250
#define V_  30000
#define F_  2048
#define FH  2048   // 4H
#define H2  1024   // 2H
#define NBLK2 256  // persistent-kernel blocks (2 dirs x 128)

// ---- static device scratch (no d_ws dependence at all) ----
__device__ u32   g_flag;                  // 1 = inputs are float32, 0 = bf16
__device__ u32   g_bar;                   // grid barrier counter
__device__ u16   g_H0[4*2*16*512];        // [(dir*2+par)][plane][16][512]
__device__ u16   g_H1[4*2*16*512];
__device__ float g_cinit[16*512];
__device__ u16   g_A1[2*2*16*1024];       // [which][plane][16][1024]
__device__ u16   g_X1[2*10*16*1024];      // [plane][row][b][1024]
__device__ u16   g_OUT1[2*800*1024];      // [plane][orow][1024]
__device__ u16   g_TOK[800*256];          // [(b*5+n)*10+r][256] bf16, e>=250 zero

DEVI f4v MFMA(s8v a, s8v b, f4v c){ return __builtin_amdgcn_mfma_f32_16x16x32_bf16(a,b,c,0,0,0); }
DEVI float bf2f(u16 u){ union{u32 i; float f;} v; v.i = ((u32)u)<<16; return v.f; }
DEVI u16 f2bf(float f){ union{float f; u32 i;} v; v.f = f; u32 i = v.i + 0x7fffu + ((v.i>>16)&1u); return (u16)(i>>16); }
DEVI float sigm(float x){ return 1.0f/(1.0f+__expf(-x)); }
DEVI float tanhfast(float x){ float e = __expf(2.0f*x); return 1.0f - 2.0f/(e+1.0f); }

DEVI s8v ld16(const u16* p){ return *(const s8v*)p; }                 // 16B-aligned
DEVI s8v ld16u(const u16* p){ s8v a; __builtin_memcpy(&a, p, 16); return a; } // 4B-aligned ok

// dtype-flexible element accessors (flag is wave-uniform)
DEVI u16 ldw(const void* W, size_t idx, int f32){
  return f32 ? f2bf(((const float*)W)[idx]) : ((const u16*)W)[idx];
}
DEVI float ldwf(const void* W, size_t idx, int f32){
  return f32 ? ((const float*)W)[idx] : bf2f(((const u16*)W)[idx]);
}
DEVI s8v ldA8(const void* A, size_t idx, int f32){
  if(f32){
    const float* p = (const float*)A + idx;
    s8v a;
    #pragma unroll
    for(int j=0;j<8;++j) a[j] = (short)f2bf(p[j]);
    return a;
  }
  return ld16u((const u16*)A + idx);
}
DEVI s8v gatherBf(const void* W, int ld, int row0, int col, int f32){
  s8v r;
  #pragma unroll
  for(int j=0;j<8;++j) r[j] = (short)ldw(W, (size_t)(row0+j)*ld + col, f32);
  return r;
}

// =====================  K0: dtype sniff + barrier reset  =====================
__global__ __launch_bounds__(64) void k0(const void* img){
  int l = threadIdx.x;
  const u16* p = (const u16*)img;
  int bad = 0;
  #pragma unroll
  for(int i=0;i<4;++i){
    float v = bf2f(p[l + 64*i]);      // f32 data => half these are mantissa garbage
    if(!(fabsf(v) <= 1e4f)) bad = 1;  // catches huge exponents AND NaN
  }
  unsigned long long m = __ballot(bad);
  if(l==0){ g_flag = (m != 0ull) ? 1u : 0u; g_bar = 0u; }
}

// =====================  K_tok: compact bf16 token-embedding table  =====================
__global__ __launch_bounds__(256) void k_tok(const int* caps, const void* emb){
  int f32 = (int)g_flag;
  int idx = blockIdx.x*256 + threadIdx.x;     // 0 .. 800*256-1
  int bnr = idx>>8, e = idx&255;
  int tok = caps[bnr];
  u16 v = (e < E_) ? ldw(emb, (size_t)tok*E_ + e, f32) : (u16)0;
  g_TOK[idx] = v;
}

// =====================  K1a: A1 = relu(img@Wh1+bh1), C1 = relu(img@Wc1+bc1) =====================
__global__ __launch_bounds__(256) void k1a(const void* img, const void* Wh1, const void* bh1,
                                           const void* Wc1, const void* bc1){
  int f32 = (int)g_flag;
  int w = threadIdx.x>>6, l = threadIdx.x&63, q = l>>4, c = l&15, m = l&15;
  int widx = blockIdx.x*4 + w;         // 0..127
  int which = widx>>6;                 // 0=h path, 1=c path
  int ct    = widx&63;                 // 64 col tiles
  const void* W    = which? Wc1 : Wh1;
  const void* bias = which? bc1 : bh1;
  int col = ct*16 + c;
  f4v acc = {0.f,0.f,0.f,0.f};
  for(int kc=0; kc<64; ++kc){
    s8v a = ldA8(img, (size_t)m*F_ + kc*32 + q*8, f32);
    s8v b = gatherBf(W, H2, kc*32+q*8, col, f32);
    acc = MFMA(a,b,acc);
  }
  float bi = ldwf(bias, col, f32);
  #pragma unroll
  for(int r=0;r<4;++r){
    float v = fmaxf(acc[r]+bi, 0.f);
    u16 hi = f2bf(v); u16 lo = f2bf(v - bf2f(hi));
    int rowb = q*4+r;
    g_A1[(size_t)(which*2+0)*B_*H2 + (size_t)rowb*H2 + col] = hi;
    g_A1[(size_t)(which*2+1)*B_*H2 + (size_t)rowb*H2 + col] = lo;
  }
}

// =====================  K1b: h,c = relu(A1@Wh2+bh2) etc; init H bufs (parity 0), cinit =====================
__global__ __launch_bounds__(256) void k1b(const void* Wh2, const void* bh2,
                                           const void* Wc2, const void* bc2){
  int f32 = (int)g_flag;
  int w = threadIdx.x>>6, l = threadIdx.x&63, q = l>>4, c = l&15, m = l&15;
  int widx = blockIdx.x*4 + w;         // 0..63
  int which = widx>>5;                 // 0=h, 1=c
  int ct    = widx&31;                 // 32 col tiles (H=512)
  const void* W    = which? Wc2 : Wh2;
  const void* bias = which? bc2 : bh2;
  const u16* Ab    = g_A1 + (size_t)which*2*B_*H2;
  int col = ct*16 + c;
  f4v acc = {0.f,0.f,0.f,0.f};
  for(int kc=0; kc<32; ++kc){
    s8v ah = ld16(Ab + (size_t)m*H2 + kc*32 + q*8);
    s8v al = ld16(Ab + (size_t)B_*H2 + (size_t)m*H2 + kc*32 + q*8);
    s8v b  = gatherBf(W, H_, kc*32+q*8, col, f32);
    acc = MFMA(ah,b,acc);
    acc = MFMA(al,b,acc);
  }
  float bi = ldwf(bias, col, f32);
  #pragma unroll
  for(int r=0;r<4;++r){
    float v = fmaxf(acc[r]+bi, 0.f);
    int rowb = q*4+r;
    if(which==0){
      u16 hi = f2bf(v); u16 lo = f2bf(v - bf2f(hi));
      #pragma unroll
      for(int dir=0; dir<2; ++dir){
        size_t base = (size_t)(dir*2+0)*16384;      // parity 0
        g_H0[base + 0*8192 + rowb*512 + col] = hi;  g_H0[base + 1*8192 + rowb*512 + col] = lo;
        g_H1[base + 0*8192 + rowb*512 + col] = hi;  g_H1[base + 1*8192 + rowb*512 + col] = lo;
      }
    } else {
      g_cinit[(size_t)rowb*H_ + col] = v;
    }
  }
}

// =====================  barrier (all 256 blocks co-resident; device-scope) =====================
DEVI void grid_barrier(u32 ep){
  __threadfence();                 // release
  if(threadIdx.x==0){
    __hip_atomic_fetch_add(&g_bar, 1u, __ATOMIC_RELEASE, __HIP_MEMORY_SCOPE_AGENT);
    u32 target = ep * (u32)NBLK2;
    while(__hip_atomic_load(&g_bar, __ATOMIC_RELAXED, __HIP_MEMORY_SCOPE_AGENT) < target){
      __builtin_amdgcn_s_sleep(1);
    }
  }
  __syncthreads();
  __threadfence();                 // acquire
}

// gate combine: acc holds G[batch=4q+r][col c], cols = gate(c>>2) x hcol(c&3).
DEVI float gate_combine(f4v acc, float& cs, int l){
  int base = (l & 48) | (l & 3);
  int sel  = (l >> 2) & 3;
  float G[4];
  #pragma unroll
  for(int gg=0; gg<4; ++gg){
    int src = base | (gg<<2);
    float a0 = __shfl(acc[0], src, 64);
    float a1 = __shfl(acc[1], src, 64);
    float a2 = __shfl(acc[2], src, 64);
    float a3 = __shfl(acc[3], src, 64);
    float x = (sel&1)? a1 : a0;
    float y = (sel&1)? a3 : a2;
    G[gg] = (sel&2)? y : x;
  }
  float iG = sigm(G[0]);
  float fG = sigm(G[1]);
  float gG = tanhfast(G[2]);
  float oG = sigm(G[3]);
  cs = fG*cs + iG*gG;
  return oG * tanhfast(cs);
}

// =====================  K2: persistent sequential bilstm2 x 50 =====================
// 256 blocks x 64 threads (1 wave). Block: dir = blk>=128, 4 h-cols (one 16-col MFMA tile =
// 4 gates x 4 hcols). Layer-0 weights in registers; layer-1 folded [Wih1;Whh1] in LDS (48 KB).
// c in registers; h stored hi/lo bf16.
__global__ __launch_bounds__(64) void k2(const void* Wih0f, const void* Whh0f, const void* b0f,
                                         const void* Wih0b, const void* Whh0b, const void* b0b,
                                         const void* Wih1f, const void* Whh1f, const void* b1f,
                                         const void* Wih1b, const void* Whh1b, const void* b1b){
  __shared__ u16 sw[24576];                    // 48 KB
  int f32 = (int)g_flag;
  int l = threadIdx.x;                         // 0..63
  int q = l>>4, c = l&15, m = l&15;
  int blk = blockIdx.x;
  int dir = (blk>=128)?1:0; int blkd = blk & 127;
  int hb = blkd*4;                             // wave hcol base
  int gcol = (c>>2)*512 + hb + (c&3);          // lane's G-column (gate*512 + hcol)
  const void* Wih0 = dir? Wih0b : Wih0f;
  const void* Whh0 = dir? Whh0b : Whh0f;
  const void* b0   = dir? b0b   : b0f;
  const void* Wih1 = dir? Wih1b : Wih1f;
  const void* Whh1 = dir? Whh1b : Whh1f;
  const void* b1   = dir? b1b   : b1f;

  // ---- layer-0 B-fragments in registers ----
  s8v w0[16];                                  // Whh0, K=512
  #pragma unroll
  for(int kc=0; kc<16; ++kc){
    #pragma unroll
    for(int j=0;j<8;++j) w0[kc][j] = (short)ldw(Whh0, (size_t)(kc*32+q*8+j)*FH + gcol, f32);
  }
  s8v wx[8];                                   // Wih0, K=256 (rows >= 250 zero)
  #pragma unroll
  for(int kc=0; kc<8; ++kc){
    #pragma unroll
    for(int j=0;j<8;++j){
      int row = kc*32+q*8+j;
      wx[kc][j] = (row<E_) ? (short)ldw(Wih0, (size_t)row*FH + gcol, f32) : (short)0;
    }
  }
  // ---- layer-1 B-fragments in LDS: [kc48][c16][q4][j8] ----
  for(int i=l; i<24576; i+=64){
    int kc=i>>9, rem=i&511, cc=rem>>5, qq=(rem>>3)&3, j=i&7;
    int gc = (cc>>2)*512 + hb + (cc&3);
    int row = kc*32+qq*8+j;
    sw[i] = (row < H2) ? ldw(Wih1, (size_t)row*FH + gc, f32)
                       : ldw(Whh1, (size_t)(row-H2)*FH + gc, f32);
  }
  __syncthreads();

  int bo  = q*4 + (c>>2);                      // owned batch row
  int hco = hb + (c&3);                        // owned h-col
  float c0 = g_cinit[(size_t)bo*H_ + hco];
  float c1 = c0;
  float bias0 = ldwf(b0, gcol, f32);
  float bias1 = ldwf(b1, gcol, f32);

  int p0=0, p1=0; u32 ep=0;
  for(int t=0; t<T_; ++t){
    int L = t+1;
    for(int n=0; n<N_; ++n){
      // ---------- phase A: layer0 (K = 256 emb + 512 h hi/lo) ----------
      for(int s=0; s<L; ++s){
        int row = dir ? (L-1-s) : s;
        const u16* er = g_TOK + ((size_t)(m*N_ + n)*T_ + row)*256;
        const u16* Hr = g_H0 + (size_t)(dir*2 + p0)*16384;
        f4v acc = {bias0,bias0,bias0,bias0};
        #pragma unroll
        for(int kc=0; kc<8; ++kc) acc = MFMA(ld16(er + kc*32 + q*8), wx[kc], acc);
        #pragma unroll
        for(int kc=0; kc<16; ++kc){
          acc = MFMA(ld16(Hr + (size_t)m*H_ + kc*32 + q*8), w0[kc], acc);
          acc = MFMA(ld16(Hr + 8192 + (size_t)m*H_ + kc*32 + q*8), w0[kc], acc);
        }
        float hn = gate_combine(acc, c0, l);
        u16 hi = f2bf(hn); u16 lo = f2bf(hn - bf2f(hi));
        u16* Hw = g_H0 + (size_t)(dir*2 + (p0^1))*16384;
        Hw[bo*H_ + hco] = hi;  Hw[8192 + bo*H_ + hco] = lo;
        g_X1[((size_t)row*16 + bo)*H2 + dir*H_ + hco] = hi;
        g_X1[163840 + ((size_t)row*16 + bo)*H2 + dir*H_ + hco] = lo;
        ++ep; grid_barrier(ep);
        p0 ^= 1;
      }
      // ---------- phase B: layer1 (K = 1024 X1 + 512 H1, both hi/lo) ----------
      for(int s=0; s<L; ++s){
        int row = dir ? (L-1-s) : s;
        f4v acc = {bias1,bias1,bias1,bias1};
        const u16* Xr  = g_X1 + ((size_t)row*16)*H2;
        const u16* Xr2 = Xr + 163840;
        #pragma unroll
        for(int kc=0; kc<32; ++kc){
          s8v bf = ld16(sw + kc*512 + c*32 + q*8);
          acc = MFMA(ld16(Xr  + (size_t)m*H2 + kc*32 + q*8), bf, acc);
          acc = MFMA(ld16(Xr2 + (size_t)m*H2 + kc*32 + q*8), bf, acc);
        }
        const u16* Hr = g_H1 + (size_t)(dir*2 + p1)*16384;
        #pragma unroll
        for(int kc=0; kc<16; ++kc){
          s8v bf = ld16(sw + (32+kc)*512 + c*32 + q*8);
          acc = MFMA(ld16(Hr + (size_t)m*H_ + kc*32 + q*8), bf, acc);
          acc = MFMA(ld16(Hr + 8192 + (size_t)m*H_ + kc*32 + q*8), bf, acc);
        }
        float hn = gate_combine(acc, c1, l);
        u16 hi = f2bf(hn); u16 lo = f2bf(hn - bf2f(hi));
        u16* Hw = g_H1 + (size_t)(dir*2 + (p1^1))*16384;
        Hw[bo*H_ + hco] = hi;  Hw[8192 + bo*H_ + hco] = lo;
        size_t orow = (size_t)(n*10+row)*16 + bo;
        g_OUT1[orow*H2 + dir*H_ + hco] = hi;
        g_OUT1[(size_t)800*H2 + orow*H2 + dir*H_ + hco] = lo;
        ++ep; grid_barrier(ep);
        p1 ^= 1;
      }
    }
  }
}

// =====================  K3: out = OUT1(800x1024 hi/lo) @ Wfc(1024x30000) + bfc =====================
__global__ __launch_bounds__(256,1) void k3(const void* Wfc, const void* bfc, void* out){
  int f32 = (int)g_flag;
  int w = threadIdx.x>>6, l = threadIdx.x&63, q = l>>4, c = l&15, m = l&15;
  int ct = blockIdx.x*4 + w;
  if(ct >= 1875) return;
  int col = ct*16 + c;
  s8v bfr[32];
  #pragma unroll
  for(int kc=0; kc<32; ++kc){
    #pragma unroll
    for(int j=0;j<8;++j) bfr[kc][j] = (short)ldw(Wfc, (size_t)(kc*32+q*8+j)*V_ + col, f32);
  }
  float bi = ldwf(bfc, col, f32);
  for(int rt=0; rt<50; ++rt){
    f4v acc = {0.f,0.f,0.f,0.f};
    const u16* Ah = g_OUT1 + (size_t)(rt*16 + m)*H2;
    const u16* Al = Ah + (size_t)800*H2;
    #pragma unroll
    for(int kc=0; kc<32; ++kc){
      acc = MFMA(ld16(Ah + kc*32 + q*8), bfr[kc], acc);
      acc = MFMA(ld16(Al + kc*32 + q*8), bfr[kc], acc);
    }
    if(f32){
      float* o = (float*)out;
      #pragma unroll
      for(int r=0;r<4;++r) o[(size_t)(rt*16 + q*4 + r)*V_ + col] = acc[r] + bi;
    } else {
      u16* o = (u16*)out;
      #pragma unroll
      for(int r=0;r<4;++r) o[(size_t)(rt*16 + q*4 + r)*V_ + col] = f2bf(acc[r] + bi);
    }
  }
}

// =====================  launcher  =====================
extern "C" void kernel_launch(void* const* d_in, const int* in_sizes, int n_in,
                              void* d_out, int out_size, void* d_ws, size_t ws_size,
                              hipStream_t stream){
  (void)in_sizes; (void)n_in; (void)out_size; (void)d_ws; (void)ws_size;
  const void* img  = d_in[0];
  const int*  caps = (const int*)d_in[1];
  const void* Wh1=d_in[2],  *bh1=d_in[3];
  const void* Wh2=d_in[4],  *bh2=d_in[5];
  const void* Wc1=d_in[6],  *bc1=d_in[7];
  const void* Wc2=d_in[8],  *bc2=d_in[9];
  const void* emb=d_in[10];
  const void* Wih0f=d_in[11], *Whh0f=d_in[12], *b0f=d_in[13];
  const void* Wih0b=d_in[14], *Whh0b=d_in[15], *b0b=d_in[16];
  const void* Wih1f=d_in[17], *Whh1f=d_in[18], *b1f=d_in[19];
  const void* Wih1b=d_in[20], *Whh1b=d_in[21], *b1b=d_in[22];
  const void* Wfc=d_in[23],  *bfc=d_in[24];

  hipLaunchKernelGGL(k0,    dim3(1),     dim3(64),  0, stream, img);
  hipLaunchKernelGGL(k_tok, dim3(800),   dim3(256), 0, stream, caps, emb);
  hipLaunchKernelGGL(k1a,   dim3(32),    dim3(256), 0, stream, img, Wh1, bh1, Wc1, bc1);
  hipLaunchKernelGGL(k1b,   dim3(16),    dim3(256), 0, stream, Wh2, bh2, Wc2, bc2);
  hipLaunchKernelGGL(k2,    dim3(NBLK2), dim3(64),  0, stream,
                     Wih0f, Whh0f, b0f, Wih0b, Whh0b, b0b,
                     Wih1f, Whh1f, b1f, Wih1b, Whh1b, b1b);
  hipLaunchKernelGGL(k3,    dim3(469),   dim3(256), 0, stream, Wfc, bfc, d_out);
}